// Round 9
// baseline (414.092 us; speedup 1.0000x reference)
//
#include <hip/hip_runtime.h>
#include <cstdint>

typedef unsigned short u16;
typedef unsigned long long u64;

__device__ __forceinline__ u16 f2b(float f){
  union { float f; uint32_t i; } v; v.f = f;
  uint32_t r = v.i + 0x7FFFu + ((v.i >> 16) & 1u);   // RNE
  return (u16)(r >> 16);
}
__device__ __forceinline__ float b2f(u16 u){
  union { uint32_t i; float f; } v; v.i = ((uint32_t)u) << 16; return v.f;
}
__device__ __forceinline__ float sigmoidf(float x){ return 1.0f / (1.0f + __expf(-x)); }

// ---- K0: pack allw = concat(w0,w1) rows as bf16 pairs (unchanged).
__global__ __launch_bounds__(256) void k_prep(
    const float* __restrict__ w0, const float* __restrict__ w1,
    uint32_t* __restrict__ wpk){
  int tid = threadIdx.x, blk = blockIdx.x;         // 0..127
  int b = blk >> 6;
  int j = (blk & 63) * 64 + (tid >> 2);
  int part = tid & 3;
  const float* src = (j < 2048) ? (w0 + ((size_t)(b*2048 + j))*64 + part*16)
                                : (w1 + ((size_t)(b*2048 + j - 2048))*64 + part*16);
  uint32_t* dst = wpk + ((size_t)b*4096 + j)*32 + part*8;
  float4 v0 = ((const float4*)src)[0];
  float4 v1 = ((const float4*)src)[1];
  float4 v2 = ((const float4*)src)[2];
  float4 v3 = ((const float4*)src)[3];
  uint4 o0, o1;
  o0.x = (uint32_t)f2b(v0.x) | ((uint32_t)f2b(v0.y) << 16);
  o0.y = (uint32_t)f2b(v0.z) | ((uint32_t)f2b(v0.w) << 16);
  o0.z = (uint32_t)f2b(v1.x) | ((uint32_t)f2b(v1.y) << 16);
  o0.w = (uint32_t)f2b(v1.z) | ((uint32_t)f2b(v1.w) << 16);
  o1.x = (uint32_t)f2b(v2.x) | ((uint32_t)f2b(v2.y) << 16);
  o1.y = (uint32_t)f2b(v2.z) | ((uint32_t)f2b(v2.w) << 16);
  o1.z = (uint32_t)f2b(v3.x) | ((uint32_t)f2b(v3.y) << 16);
  o1.w = (uint32_t)f2b(v3.z) | ((uint32_t)f2b(v3.w) << 16);
  ((uint4*)dst)[0] = o0;
  ((uint4*)dst)[1] = o1;
}

#define BAL8(wb) { \
  _Pragma("unroll") for (int i = 0; i < 8; ++i){ \
    u64 m0 = __ballot(a[i].x != 0.f); \
    u64 m1 = __ballot(a[i].y != 0.f); \
    u64 m2 = __ballot(a[i].z != 0.f); \
    u64 m3 = __ballot(a[i].w != 0.f); \
    if (lane == (wb) + i*4 + 0) myw = m0; \
    if (lane == (wb) + i*4 + 1) myw = m1; \
    if (lane == (wb) + i*4 + 2) myw = m2; \
    if (lane == (wb) + i*4 + 3) myw = m3; } }

#define COMPACT() \
  int c = __popcll(myw); \
  int pre = c; \
  _Pragma("unroll") \
  for (int off = 1; off < 64; off <<= 1){ \
    int tt = __shfl_up(pre, off, 64); \
    if (lane >= off) pre += tt; \
  } \
  int total = __shfl(pre, 63, 64); \
  int base = pre - c; \
  u64 m = myw; \
  while (m){ \
    int p = __builtin_ctzll(m); m &= m - 1; \
    q[wave][base++] = colhi + p*4; \
  } \
  int totP = (total + 15) & ~15; \
  if (lane < totP - total) q[wave][total + lane] = 0;

// ---- K1a: BIG rows only. One wave = one ww row (4096 cols): stream 16KB,
// ballot -> 64 words, compact, depth-8 dbuf pair-gather of bf16 w-rows + wem
// per-hit (multiply-by-mask). Low VGPR (no dep prefetch) -> high residency.
__global__ __launch_bounds__(256) void k_big(
    const float* __restrict__ ww, const float* __restrict__ wem,
    const uint32_t* __restrict__ wpk,
    u16* __restrict__ psumB, int* __restrict__ pcntB){
  __shared__ int q[4][288];
  int tid = threadIdx.x, wave = tid >> 6, lane = tid & 63;
  int wid = blockIdx.x*4 + wave;                   // 0..8191
  int half = lane >> 5, dcol = lane & 31;
  int colhi = (lane >> 2) * 256 + (lane & 3);
  float4 a[8];
  u64 myw = 0;
  const float4* r0 = (const float4*)(ww + (size_t)wid*4096) + lane;
  #pragma unroll
  for (int i = 0; i < 8; ++i) a[i] = r0[i*64];
  BAL8(0)
  #pragma unroll
  for (int i = 0; i < 8; ++i) a[i] = r0[512 + i*64];
  BAL8(32)
  COMPACT()
  int b = wid >> 12;
  const uint32_t* wub = wpk + (size_t)b*131072 + dcol;
  const float* wemRow = wem + (size_t)wid*4096;
  float accE = 0.f, accO = 0.f, vcF = 0.f;
  int nb = totP >> 4;                              // 16 rows / batch
  uint32_t g0[8], g1[8];
  float m0a[8], m1a[8];
#define GISSB(arr, wma, bi) { int bse = (bi) << 4; \
  _Pragma("unroll") for (int k2 = 0; k2 < 8; ++k2){ \
    int j = q[wave][bse + 2*k2 + half]; \
    arr[k2] = wub[(size_t)j*32]; \
    wma[k2] = wemRow[j]; } }
#define GACCB(arr, wma, bi) { int bse = (bi) << 4; \
  _Pragma("unroll") for (int k2 = 0; k2 < 8; ++k2){ \
    float sel = ((bse + 2*k2 + half) < total) ? wma[k2] : 0.f; \
    uint32_t wv = arr[k2]; \
    accE += sel * b2f((u16)wv); \
    accO += sel * b2f((u16)(wv >> 16)); \
    vcF += sel; } }
  if (nb > 0) GISSB(g0, m0a, 0)
  for (int bi = 0; bi < nb; bi += 2){
    if (bi + 1 < nb) GISSB(g1, m1a, bi + 1)
    GACCB(g0, m0a, bi)
    if (bi + 1 < nb){
      if (bi + 2 < nb) GISSB(g0, m0a, bi + 2)
      GACCB(g1, m1a, bi + 1)
    }
  }
#undef GISSB
#undef GACCB
  accE += __shfl_xor(accE, 32, 64);
  accO += __shfl_xor(accO, 32, 64);
  vcF  += __shfl_xor(vcF, 32, 64);
  if (lane < 32)
    ((uint32_t*)(psumB + (size_t)wid*64))[lane] =
      (uint32_t)f2b(accE) | ((uint32_t)f2b(accO) << 16);
  if (lane == 0) pcntB[wid] = (int)(vcF + 0.5f);
}

// ---- K1b: DEP rows + aux. One wave = one d0/d1 row (2048 cols): stream 8KB,
// ballot -> 32 words, compact, depth-8 dbuf pair-gather. Aux blocks: wop bits,
// weight packing, ghat.
__global__ __launch_bounds__(256) void k_dep(
    const float* __restrict__ d0, const float* __restrict__ d1,
    const float* __restrict__ wes, const float* __restrict__ wop,
    const uint32_t* __restrict__ wpk,
    const float* __restrict__ nh, const float* __restrict__ Wg, const float* __restrict__ bg,
    const float* __restrict__ Wf, const float* __restrict__ Wupd, const float* __restrict__ Wo,
    u16* __restrict__ psumD, int* __restrict__ pcntD,
    u64* __restrict__ bitOp, float* __restrict__ ghat,
    uint32_t* __restrict__ pkWf, uint32_t* __restrict__ pkWu, uint32_t* __restrict__ pkWo){
  __shared__ int q[4][288];
  int tid = threadIdx.x, wave = tid >> 6, lane = tid & 63;
  int bid = blockIdx.x;
  if (bid >= 2048){
    if (bid >= 2304){
      int aux = bid - 2304;                        // 0..16
      if (aux == 16){                              // ghat
        if (tid < 128){
          int b = tid >> 6, h = tid & 63;
          float g = bg[h];
          for (int d = 0; d < 64; ++d) g += nh[b*64 + d] * Wg[d*64 + h];
          float ss = g * g;
          #pragma unroll
          for (int o = 32; o > 0; o >>= 1) ss += __shfl_xor(ss, o, 64);
          ghat[b*64 + h] = g / (sqrtf(ss) + 1e-30f);
        }
        return;
      }
      for (int k = tid; k < 1024; k += 256){       // bf16-pair weight packing
        int i = aux*1024 + k;                      // 0..16383
        const float* src; uint32_t* dst; int li;
        if (i < 8192){ src = Wf; dst = pkWf; li = i; }
        else if (i < 14336){ src = Wupd; dst = pkWu; li = i - 8192; }
        else { src = Wo; dst = pkWo; li = i - 14336; }
        int k2 = li >> 6, ln = li & 63;
        dst[li] = (uint32_t)f2b(src[(2*k2)*64 + ln]) | ((uint32_t)f2b(src[(2*k2+1)*64 + ln]) << 16);
      }
      return;
    }
    // wop bits: wes & wop -> bitOp[n][o>>6]
    int w = (bid - 2048)*4 + wave;                 // 0..1023
    int ng0 = w * 8;
    #pragma unroll
    for (int i = 0; i < 8; ++i){
      int n = ng0 + i;
      float vx = wop[(size_t)n*128 + lane];
      float vy = wop[(size_t)n*128 + 64 + lane];
      float e  = wes[n];
      u64 m0 = __ballot((e != 0.f) && (vx != 0.f));
      u64 m1 = __ballot((e != 0.f) && (vy != 0.f));
      if (lane == 0) bitOp[(size_t)n*2]     = m0;
      if (lane == 1) bitOp[(size_t)n*2 + 1] = m1;
    }
    return;
  }
  int wid = bid*4 + wave;                          // 0..8191 = dep row id
  int half = lane >> 5, dcol = lane & 31;
  int colhi = (lane >> 2) * 256 + (lane & 3);
  const float* depBase; int jadd, bdep;
  if (wid < 4096){ depBase = d0 + (size_t)wid*2048; jadd = 0; bdep = wid >> 11; }
  else { int rr = wid - 4096; depBase = d1 + (size_t)rr*2048; jadd = 2048; bdep = rr >> 11; }
  float4 a[8];
  u64 myw = 0;
  {
    const float4* r2 = (const float4*)depBase + lane;
    #pragma unroll
    for (int i = 0; i < 8; ++i) a[i] = r2[i*64];
  }
  BAL8(0)
  COMPACT()
  const uint32_t* wub = wpk + (size_t)bdep*131072 + (size_t)jadd*32 + dcol;
  float accE = 0.f, accO = 0.f;
  int nb = totP >> 4;                              // 16 rows / batch
  uint32_t g0[8], g1[8];
#define GISS(arr, bi) { int bse = (bi) << 4; \
  _Pragma("unroll") for (int k2 = 0; k2 < 8; ++k2){ \
    int j = q[wave][bse + 2*k2 + half]; \
    arr[k2] = wub[(size_t)j*32]; } }
#define GACC(arr, bi) { int bse = (bi) << 4; \
  _Pragma("unroll") for (int k2 = 0; k2 < 8; ++k2){ \
    bool v = (bse + 2*k2 + half) < total; \
    uint32_t wv = arr[k2]; \
    accE += v ? b2f((u16)wv) : 0.f; \
    accO += v ? b2f((u16)(wv >> 16)) : 0.f; } }
  if (nb > 0) GISS(g0, 0)
  for (int bi = 0; bi < nb; bi += 2){
    if (bi + 1 < nb) GISS(g1, bi + 1)
    GACC(g0, bi)
    if (bi + 1 < nb){
      if (bi + 2 < nb) GISS(g0, bi + 2)
      GACC(g1, bi + 1)
    }
  }
#undef GISS
#undef GACC
  accE += __shfl_xor(accE, 32, 64);
  accO += __shfl_xor(accO, 32, 64);
  if (lane < 32)
    ((uint32_t*)(psumD + (size_t)wid*64))[lane] =
      (uint32_t)f2b(accE) | ((uint32_t)f2b(accO) << 16);
  if (lane == 0) pcntD[wid] = total;
}

// ---- K2: FUSED fin+update; per-row psum (unchanged from R8).
__global__ __launch_bounds__(256, 2) void k_mid(
    const u16* __restrict__ psumB, const int* __restrict__ pcntB,
    const u16* __restrict__ psumD, const int* __restrict__ pcntD,
    const float* __restrict__ Wwk, const float* __restrict__ bwk,
    const float* __restrict__ Wws, const float* __restrict__ bws,
    const float* __restrict__ w0, const float* __restrict__ w1,
    const float* __restrict__ gw, const float* __restrict__ ghat,
    const uint32_t* __restrict__ pkWf, const uint32_t* __restrict__ pkWu,
    const uint32_t* __restrict__ pkWo,
    const float* __restrict__ bf, const float* __restrict__ bupd, const float* __restrict__ bo,
    float* __restrict__ out, float* __restrict__ WUo){
  __shared__ uint32_t ldsU[16384];    // 64 KB union: {sWk,sWs} then {pWf,pWu,pWo}
  __shared__ float xsh[4][256];       // 4 KB
  int tid = threadIdx.x, lane = tid & 63, wave = tid >> 6;
  float* sWk = (float*)ldsU;          // [4096]
  float* sWs = (float*)ldsU + 4096;   // [4096]
  for (int i = tid; i < 1024; i += 256){
    ((float4*)sWk)[i] = ((const float4*)Wwk)[i];
    ((float4*)sWs)[i] = ((const float4*)Wws)[i];
  }
  __syncthreads();
  float bwkL = bwk[lane], bwsL = bws[lane];
  float wk[4], wsv[4], aw[4], wgv[4];
  #pragma unroll
  for (int t = 0; t < 4; ++t){
    int row = blockIdx.x*4 + wave + t*2048;        // global row 0..8191
    int b = row >> 12, n = row & 4095;
    float S = b2f(psumB[(size_t)row*64 + lane]);
    int T = pcntB[row];
    float y = (float)T * bwkL;
    #pragma unroll 8
    for (int d = 0; d < 64; ++d) y += __shfl(S, d, 64) * sWk[d*64 + lane];
    float ss = y * y;
    #pragma unroll
    for (int o = 32; o > 0; o >>= 1) ss += __shfl_xor(ss, o, 64);
    wk[t] = y / (sqrtf(ss) + 1e-30f);
    int rp = (n < 2048) ? (b*2048 + n) : (4096 + b*2048 + (n - 2048));
    float S2 = b2f(psumD[(size_t)rp*64 + lane]);
    int T2 = pcntD[rp];
    float y2 = (float)T2 * bwsL;
    #pragma unroll 8
    for (int d = 0; d < 64; ++d) y2 += __shfl(S2, d, 64) * sWs[d*64 + lane];
    float ss2 = y2 * y2;
    #pragma unroll
    for (int o = 32; o > 0; o >>= 1) ss2 += __shfl_xor(ss2, o, 64);
    wsv[t] = y2 / (sqrtf(ss2) + 1e-30f);
    aw[t] = (n < 2048) ? w0[((size_t)(b*2048 + n))*64 + lane]
                       : w1[((size_t)(b*2048 + n - 2048))*64 + lane];
    wgv[t] = (gw[b*4096 + n] != 0.f) ? ghat[b*64 + lane] : 0.f;
  }
  __syncthreads();                     // all waves done reading sWk/sWs
  uint32_t* pWf = ldsU;                // [8192]  32 KB
  uint32_t* pWu = ldsU + 8192;         // [6144]  24 KB
  uint32_t* pWo = ldsU + 14336;        // [2048]   8 KB
  for (int i = tid; i < 2048; i += 256) ((uint4*)pWf)[i] = ((const uint4*)pkWf)[i];
  for (int i = tid; i < 1536; i += 256) ((uint4*)pWu)[i] = ((const uint4*)pkWu)[i];
  for (int i = tid; i < 512;  i += 256) ((uint4*)pWo)[i] = ((const uint4*)pkWo)[i];
  __syncthreads();
  float bff = bf[lane], bup = bupd[lane], boo = bo[lane];
  #pragma unroll
  for (int t = 0; t < 4; ++t){
    int row = blockIdx.x*4 + wave + t*2048;
    int b = row >> 12, n = row & 4095;
    xsh[wave][lane] = aw[t]; xsh[wave][64 + lane] = wgv[t];
    xsh[wave][128 + lane] = wk[t]; xsh[wave][192 + lane] = wsv[t];
    float f = bff, u = bup;
    #pragma unroll 8
    for (int k2 = 0; k2 < 32; ++k2){
      float2 xv = *(const float2*)&xsh[wave][2*k2];
      uint32_t wf = pWf[k2*64 + lane];
      f += xv.x * b2f((u16)wf) + xv.y * b2f((u16)(wf >> 16));
    }
    #pragma unroll 8
    for (int k2 = 32; k2 < 128; ++k2){
      float2 xv = *(const float2*)&xsh[wave][2*k2];
      uint32_t wf = pWf[k2*64 + lane];
      uint32_t wu = pWu[(k2 - 32)*64 + lane];
      f += xv.x * b2f((u16)wf) + xv.y * b2f((u16)(wf >> 16));
      u += xv.x * b2f((u16)wu) + xv.y * b2f((u16)(wu >> 16));
    }
    f = sigmoidf(f);
    u = fmaxf(u, 0.f);
    float wu = fmaxf(f, 0.2f) * aw[t] + (1.f - f) * u;
    out[((size_t)b*4224 + n)*64 + lane] = wu;
    float o = boo;
    #pragma unroll 8
    for (int k2 = 0; k2 < 32; ++k2){
      uint32_t wo2 = pWo[k2*64 + lane];
      o += __shfl(wu, 2*k2, 64) * b2f((u16)wo2) + __shfl(wu, 2*k2 + 1, 64) * b2f((u16)(wo2 >> 16));
    }
    WUo[(size_t)row*64 + lane] = o;
  }
}

// ---- K3: fused op aggregation + epilogue (unchanged). One block per (b,o).
__global__ __launch_bounds__(256) void k_opfin(
    const u64* __restrict__ bitOp, const float* __restrict__ WUo,
    const float* __restrict__ opE,
    const float* __restrict__ Wf2, const float* __restrict__ bf2,
    const float* __restrict__ Wout, const float* __restrict__ bout,
    float* __restrict__ out){
  __shared__ float sW2[8192];   // 32 KB
  __shared__ float sWo[4096];   // 16 KB
  __shared__ int q[4][96];
  __shared__ float sacc[4][64];
  __shared__ int scnt[4];
  __shared__ float xsh[128];
  int tid = threadIdx.x, lane = tid & 63, wave = tid >> 6;
  for (int i = tid; i < 2048; i += 256) ((float4*)sW2)[i] = ((const float4*)Wf2)[i];
  for (int i = tid; i < 1024; i += 256) ((float4*)sWo)[i] = ((const float4*)Wout)[i];
  int rowIdx = blockIdx.x;                      // b*128 + o
  int b = rowIdx >> 7, o = rowIdx & 127;
  int wrd = o >> 6, bit = o & 63;
  const u64* bp = bitOp + (size_t)b*8192 + (size_t)wave*2048 + wrd;
  u64 lt = (1ULL << lane) - 1ULL;
  u64 vv[16];
  #pragma unroll
  for (int it = 0; it < 16; ++it) vv[it] = bp[(size_t)(it*64 + lane)*2];
  int cnt = 0;
  #pragma unroll
  for (int it = 0; it < 16; ++it){
    bool nz = (vv[it] >> bit) & 1ULL;
    u64 m = __ballot(nz);
    if (nz) q[wave][cnt + (int)__popcll(m & lt)] = wave*1024 + it*64 + lane;
    cnt += (int)__popcll(m);
  }
  const float* Xb = WUo + (size_t)b*4096*64 + lane;
  float acc = 0.f;
  int i = 0;
  for (; i + 8 <= cnt; i += 8){
    int4 c0 = *(const int4*)&q[wave][i];
    int4 c1 = *(const int4*)&q[wave][i + 4];
    float v0 = Xb[(size_t)c0.x*64], v1 = Xb[(size_t)c0.y*64];
    float v2 = Xb[(size_t)c0.z*64], v3 = Xb[(size_t)c0.w*64];
    float v4 = Xb[(size_t)c1.x*64], v5 = Xb[(size_t)c1.y*64];
    float v6 = Xb[(size_t)c1.z*64], v7 = Xb[(size_t)c1.w*64];
    acc += ((v0 + v1) + (v2 + v3)) + ((v4 + v5) + (v6 + v7));
  }
  for (; i < cnt; ++i) acc += Xb[(size_t)q[wave][i]*64];
  sacc[wave][lane] = acc;
  if (lane == 0) scnt[wave] = cnt;
  __syncthreads();
  if (wave == 0){
    float t = sacc[0][lane] + sacc[1][lane] + sacc[2][lane] + sacc[3][lane];
    float deg = (float)(scnt[0] + scnt[1] + scnt[2] + scnt[3]);
    float wo = t / (deg + 1e-30f);
    float e  = opE[(size_t)rowIdx*64 + lane];
    xsh[lane] = e; xsh[64 + lane] = wo;
    float f = bf2[lane], u = bout[lane];
    #pragma unroll 8
    for (int k = 0; k < 128; ++k) f += xsh[k] * sW2[k*64 + lane];
    #pragma unroll 8
    for (int d = 0; d < 64; ++d)  u += xsh[64 + d] * sWo[d*64 + lane];
    f = sigmoidf(f);
    u = fmaxf(u, 0.f);
    float res = fmaxf(f, 0.2f) * e + (1.f - f) * u;
    out[((size_t)b*4224 + 4096 + o)*64 + lane] = res;
  }
}

extern "C" void kernel_launch(void* const* d_in, const int* in_sizes, int n_in,
                              void* d_out, int out_size, void* d_ws, size_t ws_size,
                              hipStream_t stream){
  const float* w0   = (const float*)d_in[0];
  const float* w1   = (const float*)d_in[1];
  const float* nh   = (const float*)d_in[2];
  const float* opE  = (const float*)d_in[3];
  const float* wes  = (const float*)d_in[4];
  const float* wem  = (const float*)d_in[5];
  const float* wop  = (const float*)d_in[6];
  const float* ww   = (const float*)d_in[7];
  const float* d0   = (const float*)d_in[8];
  const float* d1   = (const float*)d_in[9];
  const float* gw   = (const float*)d_in[10];
  const float* Wg   = (const float*)d_in[11];
  const float* bg   = (const float*)d_in[12];
  const float* Wwk  = (const float*)d_in[13];
  const float* bwk  = (const float*)d_in[14];
  const float* Wws  = (const float*)d_in[15];
  const float* bws  = (const float*)d_in[16];
  const float* Wo   = (const float*)d_in[17];
  const float* bo   = (const float*)d_in[18];
  const float* Wupd = (const float*)d_in[19];
  const float* bupd = (const float*)d_in[20];
  const float* Wf   = (const float*)d_in[21];
  const float* bf   = (const float*)d_in[22];
  const float* Wf2  = (const float*)d_in[23];
  const float* bf2  = (const float*)d_in[24];
  const float* Wout = (const float*)d_in[25];
  const float* bout = (const float*)d_in[26];

  float* ws    = (float*)d_ws;
  float* ghat  = ws;                             // 128
  uint32_t* pkWf = (uint32_t*)(ws + 128);        // 8192 u32
  uint32_t* pkWu = (uint32_t*)(ws + 8320);       // 6144 u32
  uint32_t* pkWo = (uint32_t*)(ws + 14464);      // 2048 u32
  u64*  bitOp  = (u64*)(ws + 16512);             // 16384 u64 (32768 f32)
  u16*  psumB  = (u16*)(ws + 49280);             // 8192 rows x 64 u16 (262144 f32)
  int*  pcntB  = (int*)(ws + 311424);            // 8192 int
  u16*  psumD  = (u16*)(ws + 319616);            // 8192 rows x 64 u16 (262144 f32)
  int*  pcntD  = (int*)(ws + 581760);            // 8192 int
  float* WUo   = ws + 589952;                    // 524288 f32
  uint32_t* wpk = (uint32_t*)(ws + 1114240);     // 262144 u32 -> ws end 1376384 f32
  float* out   = (float*)d_out;

  k_prep<<<128, 256, 0, stream>>>(w0, w1, wpk);
  k_big<<<2048, 256, 0, stream>>>(ww, wem, wpk, psumB, pcntB);
  k_dep<<<2321, 256, 0, stream>>>(d0, d1, wes, wop, wpk,
                                  nh, Wg, bg, Wf, Wupd, Wo,
                                  psumD, pcntD, bitOp, ghat, pkWf, pkWu, pkWo);
  k_mid<<<512, 256, 0, stream>>>(psumB, pcntB, psumD, pcntD,
                                 Wwk, bwk, Wws, bws, w0, w1, gw, ghat,
                                 pkWf, pkWu, pkWo, bf, bupd, bo, out, WUo);
  k_opfin<<<256, 256, 0, stream>>>(bitOp, WUo, opE, Wf2, bf2, Wout, bout, out);
}

// Round 10
// 412.716 us; speedup vs baseline: 1.0033x; 1.0033x over previous
//
#include <hip/hip_runtime.h>
#include <cstdint>

typedef unsigned short u16;
typedef unsigned long long u64;

__device__ __forceinline__ u16 f2b(float f){
  union { float f; uint32_t i; } v; v.f = f;
  uint32_t r = v.i + 0x7FFFu + ((v.i >> 16) & 1u);   // RNE
  return (u16)(r >> 16);
}
__device__ __forceinline__ float b2f(u16 u){
  union { uint32_t i; float f; } v; v.i = ((uint32_t)u) << 16; return v.f;
}
__device__ __forceinline__ float sigmoidf(float x){ return 1.0f / (1.0f + __expf(-x)); }

// ---- K0: pack allw = concat(w0,w1) rows as bf16 pairs.
__global__ __launch_bounds__(256) void k_prep(
    const float* __restrict__ w0, const float* __restrict__ w1,
    uint32_t* __restrict__ wpk){
  int tid = threadIdx.x, blk = blockIdx.x;         // 0..127
  int b = blk >> 6;
  int j = (blk & 63) * 64 + (tid >> 2);
  int part = tid & 3;
  const float* src = (j < 2048) ? (w0 + ((size_t)(b*2048 + j))*64 + part*16)
                                : (w1 + ((size_t)(b*2048 + j - 2048))*64 + part*16);
  uint32_t* dst = wpk + ((size_t)b*4096 + j)*32 + part*8;
  float4 v0 = ((const float4*)src)[0];
  float4 v1 = ((const float4*)src)[1];
  float4 v2 = ((const float4*)src)[2];
  float4 v3 = ((const float4*)src)[3];
  uint4 o0, o1;
  o0.x = (uint32_t)f2b(v0.x) | ((uint32_t)f2b(v0.y) << 16);
  o0.y = (uint32_t)f2b(v0.z) | ((uint32_t)f2b(v0.w) << 16);
  o0.z = (uint32_t)f2b(v1.x) | ((uint32_t)f2b(v1.y) << 16);
  o0.w = (uint32_t)f2b(v1.z) | ((uint32_t)f2b(v1.w) << 16);
  o1.x = (uint32_t)f2b(v2.x) | ((uint32_t)f2b(v2.y) << 16);
  o1.y = (uint32_t)f2b(v2.z) | ((uint32_t)f2b(v2.w) << 16);
  o1.z = (uint32_t)f2b(v3.x) | ((uint32_t)f2b(v3.y) << 16);
  o1.w = (uint32_t)f2b(v3.z) | ((uint32_t)f2b(v3.w) << 16);
  ((uint4*)dst)[0] = o0;
  ((uint4*)dst)[1] = o1;
}

// ---- K1: FULL-ROW tasks (R8 best). Each wave: 1 big row (4096 cols, 64
// ballot words) then 1 dep row (2048 cols, 32 words). wem not streamed
// (gathered per-hit, multiply-by-mask); dep masks prefetched before the big
// gather; per-row psum/pcnt written once.
__global__ __launch_bounds__(256) void k_bits(
    const float* __restrict__ ww, const float* __restrict__ wem,
    const float* __restrict__ d0, const float* __restrict__ d1,
    const float* __restrict__ wes, const float* __restrict__ wop,
    const uint32_t* __restrict__ wpk,
    const float* __restrict__ nh, const float* __restrict__ Wg, const float* __restrict__ bg,
    const float* __restrict__ Wf, const float* __restrict__ Wupd, const float* __restrict__ Wo,
    u16* __restrict__ psumB, int* __restrict__ pcntB,
    u16* __restrict__ psumD, int* __restrict__ pcntD,
    u64* __restrict__ bitOp, float* __restrict__ ghat,
    uint32_t* __restrict__ pkWf, uint32_t* __restrict__ pkWu, uint32_t* __restrict__ pkWo){
  __shared__ int q[4][288];
  int tid = threadIdx.x, wave = tid >> 6, lane = tid & 63;
  int bid = blockIdx.x;
  if (bid >= 2048){
    if (bid >= 2304){
      int aux = bid - 2304;                        // 0..16
      if (aux == 16){                              // ghat
        if (tid < 128){
          int b = tid >> 6, h = tid & 63;
          float g = bg[h];
          for (int d = 0; d < 64; ++d) g += nh[b*64 + d] * Wg[d*64 + h];
          float ss = g * g;
          #pragma unroll
          for (int o = 32; o > 0; o >>= 1) ss += __shfl_xor(ss, o, 64);
          ghat[b*64 + h] = g / (sqrtf(ss) + 1e-30f);
        }
        return;
      }
      for (int k = tid; k < 1024; k += 256){       // bf16-pair weight packing
        int i = aux*1024 + k;                      // 0..16383
        const float* src; uint32_t* dst; int li;
        if (i < 8192){ src = Wf; dst = pkWf; li = i; }
        else if (i < 14336){ src = Wupd; dst = pkWu; li = i - 8192; }
        else { src = Wo; dst = pkWo; li = i - 14336; }
        int k2 = li >> 6, ln = li & 63;
        dst[li] = (uint32_t)f2b(src[(2*k2)*64 + ln]) | ((uint32_t)f2b(src[(2*k2+1)*64 + ln]) << 16);
      }
      return;
    }
    // wop bits: wes & wop -> bitOp[n][o>>6]
    int w = (bid - 2048)*4 + wave;                 // 0..1023
    int ng0 = w * 8;
    #pragma unroll
    for (int i = 0; i < 8; ++i){
      int n = ng0 + i;
      float vx = wop[(size_t)n*128 + lane];
      float vy = wop[(size_t)n*128 + 64 + lane];
      float e  = wes[n];
      u64 m0 = __ballot((e != 0.f) && (vx != 0.f));
      u64 m1 = __ballot((e != 0.f) && (vy != 0.f));
      if (lane == 0) bitOp[(size_t)n*2]     = m0;
      if (lane == 1) bitOp[(size_t)n*2 + 1] = m1;
    }
    return;
  }
  int wid = bid*4 + wave;                          // 0..8191 = big row = dep row id
  int half = lane >> 5, dcol = lane & 31;
  int colhi = (lane >> 2) * 256 + (lane & 3);
  float4 a[8];
  u64 myw = 0;
  // ---- BIG row: stream ww row (16 float4/lane in 2 half-groups) -> 64 words
  const float4* r0 = (const float4*)(ww + (size_t)wid*4096) + lane;
  #pragma unroll
  for (int i = 0; i < 8; ++i) a[i] = r0[i*64];
#define BAL8(wb) { \
  _Pragma("unroll") for (int i = 0; i < 8; ++i){ \
    u64 m0 = __ballot(a[i].x != 0.f); \
    u64 m1 = __ballot(a[i].y != 0.f); \
    u64 m2 = __ballot(a[i].z != 0.f); \
    u64 m3 = __ballot(a[i].w != 0.f); \
    if (lane == (wb) + i*4 + 0) myw = m0; \
    if (lane == (wb) + i*4 + 1) myw = m1; \
    if (lane == (wb) + i*4 + 2) myw = m2; \
    if (lane == (wb) + i*4 + 3) myw = m3; } }
  BAL8(0)
  #pragma unroll
  for (int i = 0; i < 8; ++i) a[i] = r0[512 + i*64];
  BAL8(32)
  // ---- compact -> queue
  int c = __popcll(myw);
  int pre = c;
  #pragma unroll
  for (int off = 1; off < 64; off <<= 1){
    int tt = __shfl_up(pre, off, 64);
    if (lane >= off) pre += tt;
  }
  int total = __shfl(pre, 63, 64);
  int base = pre - c;
  u64 m = myw;
  while (m){
    int p = __builtin_ctzll(m); m &= m - 1;
    q[wave][base++] = colhi + p*4;
  }
  int totP = (total + 31) & ~31;
  if (lane < totP - total) q[wave][total + lane] = 0;
  // ---- prefetch DEP row masks (in flight across the big gather)
  const float* depBase; int jadd, bdep;
  if (wid < 4096){ depBase = d0 + (size_t)wid*2048; jadd = 0; bdep = wid >> 11; }
  else { int rr = wid - 4096; depBase = d1 + (size_t)rr*2048; jadd = 2048; bdep = rr >> 11; }
  {
    const float4* r2 = (const float4*)depBase + lane;
    #pragma unroll
    for (int i = 0; i < 8; ++i) a[i] = r2[i*64];
  }
  // ---- BIG gather: 16-deep dbuf pair-gather + wem per-hit (multiply-by-mask)
  {
    int b = wid >> 12;
    const uint32_t* wub = wpk + (size_t)b*131072 + dcol;
    const float* wemRow = wem + (size_t)wid*4096;
    float accE = 0.f, accO = 0.f, vcF = 0.f;
    int nb = totP >> 5;
    uint32_t g0[16], g1[16];
    float m0a[16], m1a[16];
#define GISSB(arr, wma, bi) { int bse = (bi) << 5; \
  _Pragma("unroll") for (int k2 = 0; k2 < 16; ++k2){ \
    int j = q[wave][bse + 2*k2 + half]; \
    arr[k2] = wub[(size_t)j*32]; \
    wma[k2] = wemRow[j]; } }
#define GACCB(arr, wma, bi) { int bse = (bi) << 5; \
  _Pragma("unroll") for (int k2 = 0; k2 < 16; ++k2){ \
    float sel = ((bse + 2*k2 + half) < total) ? wma[k2] : 0.f; \
    uint32_t wv = arr[k2]; \
    accE += sel * b2f((u16)wv); \
    accO += sel * b2f((u16)(wv >> 16)); \
    vcF += sel; } }
    if (nb > 0) GISSB(g0, m0a, 0)
    for (int bi = 0; bi < nb; bi += 2){
      if (bi + 1 < nb) GISSB(g1, m1a, bi + 1)
      GACCB(g0, m0a, bi)
      if (bi + 1 < nb){
        if (bi + 2 < nb) GISSB(g0, m0a, bi + 2)
        GACCB(g1, m1a, bi + 1)
      }
    }
#undef GISSB
#undef GACCB
    accE += __shfl_xor(accE, 32, 64);
    accO += __shfl_xor(accO, 32, 64);
    vcF  += __shfl_xor(vcF, 32, 64);
    if (lane < 32)
      ((uint32_t*)(psumB + (size_t)wid*64))[lane] =
        (uint32_t)f2b(accE) | ((uint32_t)f2b(accO) << 16);
    if (lane == 0) pcntB[wid] = (int)(vcF + 0.5f);
  }
  // ---- DEP row: ballot prefetched masks (32 words) -> queue -> gather
  myw = 0;
  BAL8(0)
#undef BAL8
  c = __popcll(myw);
  pre = c;
  #pragma unroll
  for (int off = 1; off < 64; off <<= 1){
    int tt = __shfl_up(pre, off, 64);
    if (lane >= off) pre += tt;
  }
  total = __shfl(pre, 63, 64);
  base = pre - c;
  m = myw;
  while (m){
    int p = __builtin_ctzll(m); m &= m - 1;
    q[wave][base++] = colhi + p*4;
  }
  totP = (total + 31) & ~31;
  if (lane < totP - total) q[wave][total + lane] = 0;
  {
    const uint32_t* wub = wpk + (size_t)bdep*131072 + (size_t)jadd*32 + dcol;
    float accE = 0.f, accO = 0.f;
    int nb = totP >> 5;
    uint32_t g0[16], g1[16];
#define GISS(arr, bi) { int bse = (bi) << 5; \
  _Pragma("unroll") for (int k2 = 0; k2 < 16; ++k2){ \
    int j = q[wave][bse + 2*k2 + half]; \
    arr[k2] = wub[(size_t)j*32]; } }
#define GACC(arr, bi) { int bse = (bi) << 5; \
  _Pragma("unroll") for (int k2 = 0; k2 < 16; ++k2){ \
    bool v = (bse + 2*k2 + half) < total; \
    uint32_t wv = arr[k2]; \
    accE += v ? b2f((u16)wv) : 0.f; \
    accO += v ? b2f((u16)(wv >> 16)) : 0.f; } }
    if (nb > 0) GISS(g0, 0)
    for (int bi = 0; bi < nb; bi += 2){
      if (bi + 1 < nb) GISS(g1, bi + 1)
      GACC(g0, bi)
      if (bi + 1 < nb){
        if (bi + 2 < nb) GISS(g0, bi + 2)
        GACC(g1, bi + 1)
      }
    }
#undef GISS
#undef GACC
    accE += __shfl_xor(accE, 32, 64);
    accO += __shfl_xor(accO, 32, 64);
    if (lane < 32)
      ((uint32_t*)(psumD + (size_t)wid*64))[lane] =
        (uint32_t)f2b(accE) | ((uint32_t)f2b(accO) << 16);
    if (lane == 0) pcntD[wid] = total;
  }
}

// ---- K2: FUSED fin+update; psum per-row (single read, no combine).
__global__ __launch_bounds__(256, 2) void k_mid(
    const u16* __restrict__ psumB, const int* __restrict__ pcntB,
    const u16* __restrict__ psumD, const int* __restrict__ pcntD,
    const float* __restrict__ Wwk, const float* __restrict__ bwk,
    const float* __restrict__ Wws, const float* __restrict__ bws,
    const float* __restrict__ w0, const float* __restrict__ w1,
    const float* __restrict__ gw, const float* __restrict__ ghat,
    const uint32_t* __restrict__ pkWf, const uint32_t* __restrict__ pkWu,
    const uint32_t* __restrict__ pkWo,
    const float* __restrict__ bf, const float* __restrict__ bupd, const float* __restrict__ bo,
    float* __restrict__ out, float* __restrict__ WUo){
  __shared__ uint32_t ldsU[16384];    // 64 KB union: {sWk,sWs} then {pWf,pWu,pWo}
  __shared__ float xsh[4][256];       // 4 KB
  int tid = threadIdx.x, lane = tid & 63, wave = tid >> 6;
  float* sWk = (float*)ldsU;          // [4096]
  float* sWs = (float*)ldsU + 4096;   // [4096]
  for (int i = tid; i < 1024; i += 256){
    ((float4*)sWk)[i] = ((const float4*)Wwk)[i];
    ((float4*)sWs)[i] = ((const float4*)Wws)[i];
  }
  __syncthreads();
  float bwkL = bwk[lane], bwsL = bws[lane];
  float wk[4], wsv[4], aw[4], wgv[4];
  #pragma unroll
  for (int t = 0; t < 4; ++t){
    int row = blockIdx.x*4 + wave + t*2048;        // global row 0..8191
    int b = row >> 12, n = row & 4095;
    float S = b2f(psumB[(size_t)row*64 + lane]);
    int T = pcntB[row];
    float y = (float)T * bwkL;
    #pragma unroll 8
    for (int d = 0; d < 64; ++d) y += __shfl(S, d, 64) * sWk[d*64 + lane];
    float ss = y * y;
    #pragma unroll
    for (int o = 32; o > 0; o >>= 1) ss += __shfl_xor(ss, o, 64);
    wk[t] = y / (sqrtf(ss) + 1e-30f);
    int rp = (n < 2048) ? (b*2048 + n) : (4096 + b*2048 + (n - 2048));
    float S2 = b2f(psumD[(size_t)rp*64 + lane]);
    int T2 = pcntD[rp];
    float y2 = (float)T2 * bwsL;
    #pragma unroll 8
    for (int d = 0; d < 64; ++d) y2 += __shfl(S2, d, 64) * sWs[d*64 + lane];
    float ss2 = y2 * y2;
    #pragma unroll
    for (int o = 32; o > 0; o >>= 1) ss2 += __shfl_xor(ss2, o, 64);
    wsv[t] = y2 / (sqrtf(ss2) + 1e-30f);
    aw[t] = (n < 2048) ? w0[((size_t)(b*2048 + n))*64 + lane]
                       : w1[((size_t)(b*2048 + n - 2048))*64 + lane];
    wgv[t] = (gw[b*4096 + n] != 0.f) ? ghat[b*64 + lane] : 0.f;
  }
  __syncthreads();                     // all waves done reading sWk/sWs
  uint32_t* pWf = ldsU;                // [8192]  32 KB
  uint32_t* pWu = ldsU + 8192;         // [6144]  24 KB
  uint32_t* pWo = ldsU + 14336;        // [2048]   8 KB
  for (int i = tid; i < 2048; i += 256) ((uint4*)pWf)[i] = ((const uint4*)pkWf)[i];
  for (int i = tid; i < 1536; i += 256) ((uint4*)pWu)[i] = ((const uint4*)pkWu)[i];
  for (int i = tid; i < 512;  i += 256) ((uint4*)pWo)[i] = ((const uint4*)pkWo)[i];
  __syncthreads();
  float bff = bf[lane], bup = bupd[lane], boo = bo[lane];
  #pragma unroll
  for (int t = 0; t < 4; ++t){
    int row = blockIdx.x*4 + wave + t*2048;
    int b = row >> 12, n = row & 4095;
    xsh[wave][lane] = aw[t]; xsh[wave][64 + lane] = wgv[t];
    xsh[wave][128 + lane] = wk[t]; xsh[wave][192 + lane] = wsv[t];
    float f = bff, u = bup;
    #pragma unroll 8
    for (int k2 = 0; k2 < 32; ++k2){
      float2 xv = *(const float2*)&xsh[wave][2*k2];
      uint32_t wf = pWf[k2*64 + lane];
      f += xv.x * b2f((u16)wf) + xv.y * b2f((u16)(wf >> 16));
    }
    #pragma unroll 8
    for (int k2 = 32; k2 < 128; ++k2){
      float2 xv = *(const float2*)&xsh[wave][2*k2];
      uint32_t wf = pWf[k2*64 + lane];
      uint32_t wu = pWu[(k2 - 32)*64 + lane];
      f += xv.x * b2f((u16)wf) + xv.y * b2f((u16)(wf >> 16));
      u += xv.x * b2f((u16)wu) + xv.y * b2f((u16)(wu >> 16));
    }
    f = sigmoidf(f);
    u = fmaxf(u, 0.f);
    float wu = fmaxf(f, 0.2f) * aw[t] + (1.f - f) * u;
    out[((size_t)b*4224 + n)*64 + lane] = wu;
    float o = boo;
    #pragma unroll 8
    for (int k2 = 0; k2 < 32; ++k2){
      uint32_t wo2 = pWo[k2*64 + lane];
      o += __shfl(wu, 2*k2, 64) * b2f((u16)wo2) + __shfl(wu, 2*k2 + 1, 64) * b2f((u16)(wo2 >> 16));
    }
    WUo[(size_t)row*64 + lane] = o;
  }
}

// ---- K3: fused op aggregation + epilogue. One block per (b,o).
__global__ __launch_bounds__(256) void k_opfin(
    const u64* __restrict__ bitOp, const float* __restrict__ WUo,
    const float* __restrict__ opE,
    const float* __restrict__ Wf2, const float* __restrict__ bf2,
    const float* __restrict__ Wout, const float* __restrict__ bout,
    float* __restrict__ out){
  __shared__ float sW2[8192];   // 32 KB
  __shared__ float sWo[4096];   // 16 KB
  __shared__ int q[4][96];
  __shared__ float sacc[4][64];
  __shared__ int scnt[4];
  __shared__ float xsh[128];
  int tid = threadIdx.x, lane = tid & 63, wave = tid >> 6;
  for (int i = tid; i < 2048; i += 256) ((float4*)sW2)[i] = ((const float4*)Wf2)[i];
  for (int i = tid; i < 1024; i += 256) ((float4*)sWo)[i] = ((const float4*)Wout)[i];
  int rowIdx = blockIdx.x;                      // b*128 + o
  int b = rowIdx >> 7, o = rowIdx & 127;
  int wrd = o >> 6, bit = o & 63;
  const u64* bp = bitOp + (size_t)b*8192 + (size_t)wave*2048 + wrd;
  u64 lt = (1ULL << lane) - 1ULL;
  u64 vv[16];
  #pragma unroll
  for (int it = 0; it < 16; ++it) vv[it] = bp[(size_t)(it*64 + lane)*2];
  int cnt = 0;
  #pragma unroll
  for (int it = 0; it < 16; ++it){
    bool nz = (vv[it] >> bit) & 1ULL;
    u64 m = __ballot(nz);
    if (nz) q[wave][cnt + (int)__popcll(m & lt)] = wave*1024 + it*64 + lane;
    cnt += (int)__popcll(m);
  }
  const float* Xb = WUo + (size_t)b*4096*64 + lane;
  float acc = 0.f;
  int i = 0;
  for (; i + 8 <= cnt; i += 8){
    int4 c0 = *(const int4*)&q[wave][i];
    int4 c1 = *(const int4*)&q[wave][i + 4];
    float v0 = Xb[(size_t)c0.x*64], v1 = Xb[(size_t)c0.y*64];
    float v2 = Xb[(size_t)c0.z*64], v3 = Xb[(size_t)c0.w*64];
    float v4 = Xb[(size_t)c1.x*64], v5 = Xb[(size_t)c1.y*64];
    float v6 = Xb[(size_t)c1.z*64], v7 = Xb[(size_t)c1.w*64];
    acc += ((v0 + v1) + (v2 + v3)) + ((v4 + v5) + (v6 + v7));
  }
  for (; i < cnt; ++i) acc += Xb[(size_t)q[wave][i]*64];
  sacc[wave][lane] = acc;
  if (lane == 0) scnt[wave] = cnt;
  __syncthreads();
  if (wave == 0){
    float t = sacc[0][lane] + sacc[1][lane] + sacc[2][lane] + sacc[3][lane];
    float deg = (float)(scnt[0] + scnt[1] + scnt[2] + scnt[3]);
    float wo = t / (deg + 1e-30f);
    float e  = opE[(size_t)rowIdx*64 + lane];
    xsh[lane] = e; xsh[64 + lane] = wo;
    float f = bf2[lane], u = bout[lane];
    #pragma unroll 8
    for (int k = 0; k < 128; ++k) f += xsh[k] * sW2[k*64 + lane];
    #pragma unroll 8
    for (int d = 0; d < 64; ++d)  u += xsh[64 + d] * sWo[d*64 + lane];
    f = sigmoidf(f);
    u = fmaxf(u, 0.f);
    float res = fmaxf(f, 0.2f) * e + (1.f - f) * u;
    out[((size_t)b*4224 + 4096 + o)*64 + lane] = res;
  }
}

extern "C" void kernel_launch(void* const* d_in, const int* in_sizes, int n_in,
                              void* d_out, int out_size, void* d_ws, size_t ws_size,
                              hipStream_t stream){
  const float* w0   = (const float*)d_in[0];
  const float* w1   = (const float*)d_in[1];
  const float* nh   = (const float*)d_in[2];
  const float* opE  = (const float*)d_in[3];
  const float* wes  = (const float*)d_in[4];
  const float* wem  = (const float*)d_in[5];
  const float* wop  = (const float*)d_in[6];
  const float* ww   = (const float*)d_in[7];
  const float* d0   = (const float*)d_in[8];
  const float* d1   = (const float*)d_in[9];
  const float* gw   = (const float*)d_in[10];
  const float* Wg   = (const float*)d_in[11];
  const float* bg   = (const float*)d_in[12];
  const float* Wwk  = (const float*)d_in[13];
  const float* bwk  = (const float*)d_in[14];
  const float* Wws  = (const float*)d_in[15];
  const float* bws  = (const float*)d_in[16];
  const float* Wo   = (const float*)d_in[17];
  const float* bo   = (const float*)d_in[18];
  const float* Wupd = (const float*)d_in[19];
  const float* bupd = (const float*)d_in[20];
  const float* Wf   = (const float*)d_in[21];
  const float* bf   = (const float*)d_in[22];
  const float* Wf2  = (const float*)d_in[23];
  const float* bf2  = (const float*)d_in[24];
  const float* Wout = (const float*)d_in[25];
  const float* bout = (const float*)d_in[26];

  float* ws    = (float*)d_ws;
  float* ghat  = ws;                             // 128
  uint32_t* pkWf = (uint32_t*)(ws + 128);        // 8192 u32
  uint32_t* pkWu = (uint32_t*)(ws + 8320);       // 6144 u32
  uint32_t* pkWo = (uint32_t*)(ws + 14464);      // 2048 u32
  u64*  bitOp  = (u64*)(ws + 16512);             // 16384 u64 (32768 f32)
  u16*  psumB  = (u16*)(ws + 49280);             // 8192 rows x 64 u16 (262144 f32)
  int*  pcntB  = (int*)(ws + 311424);            // 8192 int
  u16*  psumD  = (u16*)(ws + 319616);            // 8192 rows x 64 u16 (262144 f32)
  int*  pcntD  = (int*)(ws + 581760);            // 8192 int
  float* WUo   = ws + 589952;                    // 524288 f32
  uint32_t* wpk = (uint32_t*)(ws + 1114240);     // 262144 u32 -> ws end 1376384 f32
  float* out   = (float*)d_out;

  k_prep<<<128, 256, 0, stream>>>(w0, w1, wpk);
  k_bits<<<2321, 256, 0, stream>>>(ww, wem, d0, d1, wes, wop, wpk,
                                   nh, Wg, bg, Wf, Wupd, Wo,
                                   psumB, pcntB, psumD, pcntD,
                                   bitOp, ghat, pkWf, pkWu, pkWo);
  k_mid<<<512, 256, 0, stream>>>(psumB, pcntB, psumD, pcntD,
                                 Wwk, bwk, Wws, bws, w0, w1, gw, ghat,
                                 pkWf, pkWu, pkWo, bf, bupd, bo, out, WUo);
  k_opfin<<<256, 256, 0, stream>>>(bitOp, WUo, opE, Wf2, bf2, Wout, bout, out);
}